// Round 10
// baseline (169.238 us; speedup 1.0000x reference)
//
#include <hip/hip_runtime.h>
#include <stdint.h>

// DCNv2 forward, MI355X — R9: main_gemm goes LDS-free (direct-fragment GEMM).
//  K0 prep_and_transpose : x NCHW fp32 -> xt NHWC bf16; W -> WB bf16 B-frag
//     order [kk/8][o][8]; p_weight -> PWs (N=32 pad); zeropage.
//  K1 offset_conv_sk : split-K (S=8) implicit-im2col bf16 MFMA conv, BM=64,
//     XCD-swizzled; A staged via global_load_lds from bf16 xt (OOB->zeropage).
//  K2 sample9 : one wave per m, 9 taps; inline finalize of 36 descriptors in
//     LDS; bilinear bf16 corners -> Amat bf16 [m][kk] (= A-fragment order).
//  K3 main_gemm : 128x64 tile, NO LDS: A and B fragments loaded directly
//     global->VGPR (Amat/WB are already in fragment order). No barriers in
//     K-loop -> compiler software-pipelines; kills the 17us ds_read floor and
//     all vmcnt(0) drains. Grid (128,4)=512 blocks; 4 n-blocks of an m-tile
//     share an XCD (id stride 128 = 0 mod 8) so A re-reads stay in local L2.
// Workspace ~102 MB of 256 MiB.

#define CIN 256
#define COUT 256
#define HWS 4096      // H*W
#define MTOT 16384    // B*H*W
#define KTOT 2304     // CIN*9
#define SPLITK 8

typedef __attribute__((ext_vector_type(8))) short bf16x8;
typedef __attribute__((ext_vector_type(4))) float f32x4;

__device__ __forceinline__ unsigned short f2bf(float f) {
  unsigned int u = __float_as_uint(f);
  unsigned int r = (u + 0x7fffu + ((u >> 16) & 1u)) >> 16;
  return (unsigned short)r;
}
__device__ __forceinline__ float bf2f(unsigned short u) {
  return __uint_as_float(((unsigned int)u) << 16);
}

__device__ __forceinline__ void gload_lds16(const void* g, void* l) {
  __builtin_amdgcn_global_load_lds((const __attribute__((address_space(1))) void*)g,
                                   (__attribute__((address_space(3))) void*)l, 16, 0, 0);
}

// ---------------- K0: fused transpose (NCHW fp32 -> NHWC bf16) + weight prep ----------------
__global__ __launch_bounds__(256) void prep_and_transpose(const float* __restrict__ x,
                                                          const float* __restrict__ w,
                                                          const float* __restrict__ pw,
                                                          unsigned short* __restrict__ xt,
                                                          unsigned short* __restrict__ WB,
                                                          unsigned short* __restrict__ PWs,
                                                          unsigned short* __restrict__ zerop) {
  __shared__ float tile[32][33];
  int bid = blockIdx.x;
  if (bid < 4096) {
    int b = bid >> 10;
    int rest = bid & 1023;
    int hw0 = (rest & 127) * 32;
    int c0 = ((rest >> 7) & 7) * 32;
    int tx = threadIdx.x & 31, ty = threadIdx.x >> 5;
    for (int i = ty; i < 32; i += 8)
      tile[i][tx] = x[(size_t)(b * CIN + c0 + i) * HWS + hw0 + tx];
    __syncthreads();
    for (int r = ty; r < 32; r += 8)
      xt[(size_t)(b * HWS + hw0 + r) * CIN + c0 + tx] = f2bf(tile[tx][r]);
  } else {
    int idx = (bid - 4096) * 256 + threadIdx.x;
    if (idx < 512)
      *(uint4*)(zerop + idx * 8) = make_uint4(0, 0, 0, 0);
    if (idx < KTOT * COUT) {
      int f = idx;
      int t_ = f & 7;
      int rest = f >> 3;
      int o = rest & 255;
      int kk = (rest >> 8) * 8 + t_;
      int k = kk >> 8, c = kk & 255;
      WB[f] = f2bf(w[o * KTOT + c * 9 + k]);
    } else {
      int f2 = idx - KTOT * COUT;   // < 2304*32
      int t_ = f2 & 7;
      int rest = f2 >> 3;
      int j = rest & 31;
      int kk = (rest >> 5) * 8 + t_;
      int k = kk >> 8, c = kk & 255;
      float v = (j < 27) ? pw[j * KTOT + c * 9 + k] : 0.0f;
      PWs[f2] = f2bf(v);
    }
  }
}

// ---------------- K1: offset conv, split-K, BM=64, bf16-xt global_load_lds staging ----------------
__global__ __launch_bounds__(256) void offset_conv_sk(const unsigned short* __restrict__ xt,
                                                      const unsigned short* __restrict__ PWs,
                                                      const unsigned short* __restrict__ zerop,
                                                      float* __restrict__ Pbuf) {
  __shared__ unsigned short Al[64 * 32];   // 4 KB
  __shared__ unsigned short Bl[1024];      // 2 KB
  int tid = threadIdx.x;
  int lane = tid & 63, wv = tid >> 6;
  int mt = (blockIdx.x & 7) * 32 + (blockIdx.x >> 3);   // XCD swizzle
  int m0 = mt * 64;
  int s = blockIdx.y;
  int b = m0 >> 12;
  int hw0 = m0 & 4095;
  f32x4 acc[2] = {};

  for (int tt = 0; tt < 72 / SPLITK; ++tt) {
    int t = s * (72 / SPLITK) + tt;
    int k = t >> 3, c0 = (t & 7) * 32;
    int dyk = k / 3 - 1;
    int dxk = k % 3 - 1;
    __syncthreads();
    if (tid < 128)
      gload_lds16(PWs + (size_t)t * 1024 + tid * 8, &Bl[tid * 8]);
    {
      int r = tid >> 2;
      int hw = hw0 + r;
      int h = hw >> 6, wwp = hw & 63;
      int y = h + dyk, xx = wwp + dxk;
      bool valid = ((unsigned)y < 64u) && ((unsigned)xx < 64u);
      const unsigned short* src = valid
          ? xt + ((size_t)((b << 12) + (y << 6) + xx) << 8) + c0 + (tid & 3) * 8
          : zerop;
      gload_lds16(src, &Al[tid * 8]);
    }
    __syncthreads();
    int row = lane & 15, quad = lane >> 4;
    bf16x8 af = *(const bf16x8*)&Al[(wv * 16 + row) * 32 + quad * 8];
    for (int j = 0; j < 2; ++j) {
      bf16x8 bfr = *(const bf16x8*)&Bl[(quad * 32 + j * 16 + row) * 8];
      acc[j] = __builtin_amdgcn_mfma_f32_16x16x32_bf16(af, bfr, acc[j], 0, 0, 0);
    }
  }

  int row = lane & 15, quad = lane >> 4;
  for (int j = 0; j < 2; ++j) {
    int n = j * 16 + row;
    for (int r_ = 0; r_ < 4; ++r_) {
      int m = m0 + wv * 16 + quad * 4 + r_;
      Pbuf[((size_t)s * MTOT + m) * 32 + n] = acc[j][r_];
    }
  }
}

// ---------------- K2: sample9 with inline tap finalize ----------------
__global__ __launch_bounds__(256) void sample9(const unsigned short* __restrict__ xt,
                                               const float* __restrict__ Pbuf,
                                               const float* __restrict__ p_bias,
                                               unsigned short* __restrict__ A) {
  __shared__ int4 dI[4][9];
  __shared__ float4 dW[4][9];
  int tid = threadIdx.x;
  int reg = blockIdx.x & 7;                     // XCD region (matches K1)
  int mb = reg * 2048 + (blockIdx.x >> 3) * 4;  // base m of this block

  if (tid < 36) {
    int lm = tid / 9, k = tid - lm * 9;
    int m = mb + lm;
    float dy = p_bias[2 * k];
    float dx = p_bias[2 * k + 1];
    float mv = p_bias[18 + k];
#pragma unroll
    for (int s = 0; s < SPLITK; ++s) {
      const float* p = Pbuf + ((size_t)s * MTOT + m) * 32;
      dy += p[2 * k];
      dx += p[2 * k + 1];
      mv += p[18 + k];
    }
    float mk = 1.0f / (1.0f + __expf(-mv));

    int hw = m & 4095, h = hw >> 6, ww = hw & 63;
    float py = (float)(h - 1 + k / 3) + dy;
    float px = (float)(ww - 1 + k % 3) + dx;
    float y0f = floorf(py), x0f = floorf(px);
    float ay = py - y0f, ax = px - x0f;
    int y0 = (int)y0f, x0 = (int)x0f;

    float w00 = (1.f - ay) * (1.f - ax) * mk;
    float w01 = (1.f - ay) * ax * mk;
    float w10 = ay * (1.f - ax) * mk;
    float w11 = ay * ax * mk;

    float vy0 = ((unsigned)y0 < 64u) ? 1.f : 0.f;
    float vy1 = ((unsigned)(y0 + 1) < 64u) ? 1.f : 0.f;
    float vx0 = ((unsigned)x0 < 64u) ? 1.f : 0.f;
    float vx1 = ((unsigned)(x0 + 1) < 64u) ? 1.f : 0.f;
    w00 *= vy0 * vx0; w01 *= vy0 * vx1; w10 *= vy1 * vx0; w11 *= vy1 * vx1;

    int yc0 = min(max(y0, 0), 63), yc1 = min(max(y0 + 1, 0), 63);
    int xc0 = min(max(x0, 0), 63), xc1 = min(max(x0 + 1, 0), 63);

    dI[lm][k] = make_int4((yc0 * 64 + xc0) * 256, (yc0 * 64 + xc1) * 256,
                          (yc1 * 64 + xc0) * 256, (yc1 * 64 + xc1) * 256);
    dW[lm][k] = make_float4(w00, w01, w10, w11);
  }
  __syncthreads();

  int wv = tid >> 6, lane = tid & 63;
  int m = mb + wv;
  int b = m >> 12;
  const unsigned short* xtb = xt + (((size_t)b << 12) << 8);
  unsigned short* outp = A + (size_t)m * KTOT + lane * 4;

#pragma unroll
  for (int k = 0; k < 9; ++k) {
    int4 o4 = dI[wv][k];       // LDS broadcast — free
    float4 w4 = dW[wv][k];
    ushort4 t00 = *(const ushort4*)(xtb + o4.x + 4 * lane);
    ushort4 t01 = *(const ushort4*)(xtb + o4.y + 4 * lane);
    ushort4 t10 = *(const ushort4*)(xtb + o4.z + 4 * lane);
    ushort4 t11 = *(const ushort4*)(xtb + o4.w + 4 * lane);
    float r0 = w4.x * bf2f(t00.x) + w4.y * bf2f(t01.x) + w4.z * bf2f(t10.x) + w4.w * bf2f(t11.x);
    float r1 = w4.x * bf2f(t00.y) + w4.y * bf2f(t01.y) + w4.z * bf2f(t10.y) + w4.w * bf2f(t11.y);
    float r2 = w4.x * bf2f(t00.z) + w4.y * bf2f(t01.z) + w4.z * bf2f(t10.z) + w4.w * bf2f(t11.z);
    float r3 = w4.x * bf2f(t00.w) + w4.y * bf2f(t01.w) + w4.z * bf2f(t10.w) + w4.w * bf2f(t11.w);
    ushort4 o;
    o.x = f2bf(r0); o.y = f2bf(r1); o.z = f2bf(r2); o.w = f2bf(r3);
    *(ushort4*)(outp + k * 256) = o;
  }
}

// ---------------- K3: main GEMM 128x64, NO LDS — direct fragment loads ----------------
// A-frag: Amat[(m0+wm+i*16+row)*KTOT + t*32 + quad*8]  (16B/lane, 16 64B lines)
// B-frag: WB[((t*4+quad)*256 + n0 + j*16 + row)*8]     (256B contiguous/quad)
// No barriers in the K-loop: compiler pipelines loads across iterations.
__global__ __launch_bounds__(256) void main_gemm(const unsigned short* __restrict__ Amat,
                                                 const unsigned short* __restrict__ WB,
                                                 const float* __restrict__ bias,
                                                 float* __restrict__ out) {
  int tid = threadIdx.x;
  int lane = tid & 63, wv = tid >> 6;
  int m0 = blockIdx.x * 128;
  int n0 = blockIdx.y * 64;
  int wm = wv * 32;
  int row = lane & 15, quad = lane >> 4;
  f32x4 acc[2][4] = {};

  const unsigned short* aptr0 = Amat + (size_t)(m0 + wm + row) * KTOT + quad * 8;
  const unsigned short* aptr1 = aptr0 + (size_t)16 * KTOT;
  const unsigned short* bptr = WB + ((size_t)quad * 256 + n0 + row) * 8;
  // iter t: A += t*32 ; B += t*8192, j-tile stride 128 (ushorts)

#pragma unroll 4
  for (int t = 0; t < 72; ++t) {
    bf16x8 a0 = *(const bf16x8*)(aptr0 + t * 32);
    bf16x8 a1 = *(const bf16x8*)(aptr1 + t * 32);
    const unsigned short* bt = bptr + t * 8192;
    bf16x8 b0 = *(const bf16x8*)(bt);
    bf16x8 b1 = *(const bf16x8*)(bt + 128);
    bf16x8 b2 = *(const bf16x8*)(bt + 256);
    bf16x8 b3 = *(const bf16x8*)(bt + 384);
    acc[0][0] = __builtin_amdgcn_mfma_f32_16x16x32_bf16(a0, b0, acc[0][0], 0, 0, 0);
    acc[0][1] = __builtin_amdgcn_mfma_f32_16x16x32_bf16(a0, b1, acc[0][1], 0, 0, 0);
    acc[0][2] = __builtin_amdgcn_mfma_f32_16x16x32_bf16(a0, b2, acc[0][2], 0, 0, 0);
    acc[0][3] = __builtin_amdgcn_mfma_f32_16x16x32_bf16(a0, b3, acc[0][3], 0, 0, 0);
    acc[1][0] = __builtin_amdgcn_mfma_f32_16x16x32_bf16(a1, b0, acc[1][0], 0, 0, 0);
    acc[1][1] = __builtin_amdgcn_mfma_f32_16x16x32_bf16(a1, b1, acc[1][1], 0, 0, 0);
    acc[1][2] = __builtin_amdgcn_mfma_f32_16x16x32_bf16(a1, b2, acc[1][2], 0, 0, 0);
    acc[1][3] = __builtin_amdgcn_mfma_f32_16x16x32_bf16(a1, b3, acc[1][3], 0, 0, 0);
  }

  int b = m0 >> 12, hw0 = m0 & 4095;
#pragma unroll
  for (int j = 0; j < 4; ++j) {
    int o = n0 + j * 16 + row;
    float bo = bias[o];
#pragma unroll
    for (int i = 0; i < 2; ++i) {
      int hw = hw0 + wm + i * 16 + quad * 4;
      float4 v;
      v.x = acc[i][j][0] + bo;
      v.y = acc[i][j][1] + bo;
      v.z = acc[i][j][2] + bo;
      v.w = acc[i][j][3] + bo;
      *(float4*)(out + (((size_t)(b * COUT + o)) << 12) + hw) = v;
    }
  }
}

// ---------------- launch ----------------
extern "C" void kernel_launch(void* const* d_in, const int* in_sizes, int n_in,
                              void* d_out, int out_size, void* d_ws, size_t ws_size,
                              hipStream_t stream) {
  const float* x        = (const float*)d_in[0];
  const float* weight   = (const float*)d_in[1];
  const float* bias     = (const float*)d_in[2];
  const float* p_weight = (const float*)d_in[3];
  const float* p_bias   = (const float*)d_in[4];
  float* out = (float*)d_out;
  char* ws = (char*)d_ws;

  // workspace layout (bytes); total ~102 MB of 256 MiB
  const size_t OFF_XT   = 0;                          //  8,388,608  bf16 NHWC x
  const size_t OFF_WB   = OFF_XT + 8388608;           //  1,179,648  bf16
  const size_t OFF_PW   = OFF_WB + 1179648;           //    147,456  bf16
  const size_t OFF_P    = OFF_PW + 147456;            // 16,777,216  fp32 partials
  const size_t OFF_ZP   = OFF_P + 16777216;           //      8,192  zeropage
  const size_t OFF_A    = OFF_ZP + 8192;              // 75,497,472  bf16 Amat

  unsigned short* xt    = (unsigned short*)(ws + OFF_XT);
  unsigned short* WB    = (unsigned short*)(ws + OFF_WB);
  unsigned short* PWs   = (unsigned short*)(ws + OFF_PW);
  float* Pbuf           = (float*)(ws + OFF_P);
  unsigned short* zerop = (unsigned short*)(ws + OFF_ZP);
  unsigned short* Amat  = (unsigned short*)(ws + OFF_A);

  prep_and_transpose<<<4096 + 2592, 256, 0, stream>>>(x, weight, p_weight, xt, WB, PWs, zerop);
  offset_conv_sk<<<dim3(MTOT / 64, SPLITK), 256, 0, stream>>>(xt, PWs, zerop, Pbuf);
  sample9<<<MTOT / 4, 256, 0, stream>>>(xt, Pbuf, p_bias, Amat);
  main_gemm<<<dim3(MTOT / 128, COUT / 64), 256, 0, stream>>>(Amat, WB, bias, out);
}

// Round 11
// 150.312 us; speedup vs baseline: 1.1259x; 1.1259x over previous
//
#include <hip/hip_runtime.h>
#include <stdint.h>

// DCNv2 forward, MI355X — R10: LDS-free main GEMM with COALESCED fragment
// layouts (R9 failed on 16-way-scattered A loads; layouts now make every
// fragment load one contiguous 1KB wave transaction).
//  K0 prep_and_transpose : x NCHW fp32 -> xt NHWC bf16; W -> WB2 bf16 in
//     [t][j][quad][row][8] (1KB contiguous per B-fragment); PWs; zeropage.
//  K1 offset_conv_sk : split-K (S=8) implicit-im2col bf16 MFMA conv, BM=64,
//     XCD-swizzled; A staged via global_load_lds from bf16 xt.
//  K2 sample9 : one wave per m, 9 taps; inline finalize; writes A2 in
//     [m/16][t][row][quad][8] (1KB contiguous per A-fragment).
//  K3 main_gemm : 128x64, NO LDS, register double-buffered direct fragment
//     loads (6 x 1KB coalesced loads/iter), no barriers in K-loop.
// Workspace ~102 MB of 256 MiB.

#define CIN 256
#define COUT 256
#define HWS 4096      // H*W
#define MTOT 16384    // B*H*W
#define KTOT 2304     // CIN*9
#define SPLITK 8

typedef __attribute__((ext_vector_type(8))) short bf16x8;
typedef __attribute__((ext_vector_type(4))) float f32x4;

__device__ __forceinline__ unsigned short f2bf(float f) {
  unsigned int u = __float_as_uint(f);
  unsigned int r = (u + 0x7fffu + ((u >> 16) & 1u)) >> 16;
  return (unsigned short)r;
}
__device__ __forceinline__ float bf2f(unsigned short u) {
  return __uint_as_float(((unsigned int)u) << 16);
}

__device__ __forceinline__ void gload_lds16(const void* g, void* l) {
  __builtin_amdgcn_global_load_lds((const __attribute__((address_space(1))) void*)g,
                                   (__attribute__((address_space(3))) void*)l, 16, 0, 0);
}

// ---------------- K0: fused transpose + weight prep (WB2 frag-block order) ----------------
__global__ __launch_bounds__(256) void prep_and_transpose(const float* __restrict__ x,
                                                          const float* __restrict__ w,
                                                          const float* __restrict__ pw,
                                                          unsigned short* __restrict__ xt,
                                                          unsigned short* __restrict__ WB,
                                                          unsigned short* __restrict__ PWs,
                                                          unsigned short* __restrict__ zerop) {
  __shared__ float tile[32][33];
  int bid = blockIdx.x;
  if (bid < 4096) {
    int b = bid >> 10;
    int rest = bid & 1023;
    int hw0 = (rest & 127) * 32;
    int c0 = ((rest >> 7) & 7) * 32;
    int tx = threadIdx.x & 31, ty = threadIdx.x >> 5;
    for (int i = ty; i < 32; i += 8)
      tile[i][tx] = x[(size_t)(b * CIN + c0 + i) * HWS + hw0 + tx];
    __syncthreads();
    for (int r = ty; r < 32; r += 8)
      xt[(size_t)(b * HWS + hw0 + r) * CIN + c0 + tx] = f2bf(tile[tx][r]);
  } else {
    int idx = (bid - 4096) * 256 + threadIdx.x;
    if (idx < 512)
      *(uint4*)(zerop + idx * 8) = make_uint4(0, 0, 0, 0);
    if (idx < KTOT * COUT) {
      // WB2[t][j][quad][row][8]: f = (((t*16+j)*4+quad)*16+row)*8+e
      int f = idx;
      int e = f & 7;
      int row = (f >> 3) & 15;
      int quad = (f >> 7) & 3;
      int j = (f >> 9) & 15;
      int t = f >> 13;                 // 0..71
      int kk = t * 32 + quad * 8 + e;
      int o = j * 16 + row;
      int k = kk >> 8, c = kk & 255;
      WB[f] = f2bf(w[o * KTOT + c * 9 + k]);
    } else {
      int f2 = idx - KTOT * COUT;   // < 2304*32
      int t_ = f2 & 7;
      int rest = f2 >> 3;
      int j = rest & 31;
      int kk = (rest >> 5) * 8 + t_;
      int k = kk >> 8, c = kk & 255;
      float v = (j < 27) ? pw[j * KTOT + c * 9 + k] : 0.0f;
      PWs[f2] = f2bf(v);
    }
  }
}

// ---------------- K1: offset conv, split-K, BM=64 ----------------
__global__ __launch_bounds__(256) void offset_conv_sk(const unsigned short* __restrict__ xt,
                                                      const unsigned short* __restrict__ PWs,
                                                      const unsigned short* __restrict__ zerop,
                                                      float* __restrict__ Pbuf) {
  __shared__ unsigned short Al[64 * 32];   // 4 KB
  __shared__ unsigned short Bl[1024];      // 2 KB
  int tid = threadIdx.x;
  int lane = tid & 63, wv = tid >> 6;
  int mt = (blockIdx.x & 7) * 32 + (blockIdx.x >> 3);   // XCD swizzle
  int m0 = mt * 64;
  int s = blockIdx.y;
  int b = m0 >> 12;
  int hw0 = m0 & 4095;
  f32x4 acc[2] = {};

  for (int tt = 0; tt < 72 / SPLITK; ++tt) {
    int t = s * (72 / SPLITK) + tt;
    int k = t >> 3, c0 = (t & 7) * 32;
    int dyk = k / 3 - 1;
    int dxk = k % 3 - 1;
    __syncthreads();
    if (tid < 128)
      gload_lds16(PWs + (size_t)t * 1024 + tid * 8, &Bl[tid * 8]);
    {
      int r = tid >> 2;
      int hw = hw0 + r;
      int h = hw >> 6, wwp = hw & 63;
      int y = h + dyk, xx = wwp + dxk;
      bool valid = ((unsigned)y < 64u) && ((unsigned)xx < 64u);
      const unsigned short* src = valid
          ? xt + ((size_t)((b << 12) + (y << 6) + xx) << 8) + c0 + (tid & 3) * 8
          : zerop;
      gload_lds16(src, &Al[tid * 8]);
    }
    __syncthreads();
    int row = lane & 15, quad = lane >> 4;
    bf16x8 af = *(const bf16x8*)&Al[(wv * 16 + row) * 32 + quad * 8];
    for (int j = 0; j < 2; ++j) {
      bf16x8 bfr = *(const bf16x8*)&Bl[(quad * 32 + j * 16 + row) * 8];
      acc[j] = __builtin_amdgcn_mfma_f32_16x16x32_bf16(af, bfr, acc[j], 0, 0, 0);
    }
  }

  int row = lane & 15, quad = lane >> 4;
  for (int j = 0; j < 2; ++j) {
    int n = j * 16 + row;
    for (int r_ = 0; r_ < 4; ++r_) {
      int m = m0 + wv * 16 + quad * 4 + r_;
      Pbuf[((size_t)s * MTOT + m) * 32 + n] = acc[j][r_];
    }
  }
}

// ---------------- K2: sample9, writes A2 in fragment-block order ----------------
// A2[(m>>4)][t(72)][row=m&15][quad(4)][8]; for tap k, lane covers c=4*lane..+3:
//   t = k*8 + (lane>>3), quad = (lane>>1)&3, e0 = (lane&1)*4.
__global__ __launch_bounds__(256) void sample9(const unsigned short* __restrict__ xt,
                                               const float* __restrict__ Pbuf,
                                               const float* __restrict__ p_bias,
                                               unsigned short* __restrict__ A) {
  __shared__ int4 dI[4][9];
  __shared__ float4 dW[4][9];
  int tid = threadIdx.x;
  int reg = blockIdx.x & 7;                     // XCD region (matches K1)
  int mb = reg * 2048 + (blockIdx.x >> 3) * 4;  // base m of this block

  if (tid < 36) {
    int lm = tid / 9, k = tid - lm * 9;
    int m = mb + lm;
    float dy = p_bias[2 * k];
    float dx = p_bias[2 * k + 1];
    float mv = p_bias[18 + k];
#pragma unroll
    for (int s = 0; s < SPLITK; ++s) {
      const float* p = Pbuf + ((size_t)s * MTOT + m) * 32;
      dy += p[2 * k];
      dx += p[2 * k + 1];
      mv += p[18 + k];
    }
    float mk = 1.0f / (1.0f + __expf(-mv));

    int hw = m & 4095, h = hw >> 6, ww = hw & 63;
    float py = (float)(h - 1 + k / 3) + dy;
    float px = (float)(ww - 1 + k % 3) + dx;
    float y0f = floorf(py), x0f = floorf(px);
    float ay = py - y0f, ax = px - x0f;
    int y0 = (int)y0f, x0 = (int)x0f;

    float w00 = (1.f - ay) * (1.f - ax) * mk;
    float w01 = (1.f - ay) * ax * mk;
    float w10 = ay * (1.f - ax) * mk;
    float w11 = ay * ax * mk;

    float vy0 = ((unsigned)y0 < 64u) ? 1.f : 0.f;
    float vy1 = ((unsigned)(y0 + 1) < 64u) ? 1.f : 0.f;
    float vx0 = ((unsigned)x0 < 64u) ? 1.f : 0.f;
    float vx1 = ((unsigned)(x0 + 1) < 64u) ? 1.f : 0.f;
    w00 *= vy0 * vx0; w01 *= vy0 * vx1; w10 *= vy1 * vx0; w11 *= vy1 * vx1;

    int yc0 = min(max(y0, 0), 63), yc1 = min(max(y0 + 1, 0), 63);
    int xc0 = min(max(x0, 0), 63), xc1 = min(max(x0 + 1, 0), 63);

    dI[lm][k] = make_int4((yc0 * 64 + xc0) * 256, (yc0 * 64 + xc1) * 256,
                          (yc1 * 64 + xc0) * 256, (yc1 * 64 + xc1) * 256);
    dW[lm][k] = make_float4(w00, w01, w10, w11);
  }
  __syncthreads();

  int wv = tid >> 6, lane = tid & 63;
  int m = mb + wv;
  int b = m >> 12;
  const unsigned short* xtb = xt + (((size_t)b << 12) << 8);
  // fragment-order base: block (m>>4), sub-t (lane>>3), row (m&15), quad, e0
  unsigned short* abase = A + (((size_t)(m >> 4) * 72 + (lane >> 3)) * 16 + (m & 15)) * 32
                            + ((lane >> 1) & 3) * 8 + (lane & 1) * 4;

#pragma unroll
  for (int k = 0; k < 9; ++k) {
    int4 o4 = dI[wv][k];       // LDS broadcast — free
    float4 w4 = dW[wv][k];
    ushort4 t00 = *(const ushort4*)(xtb + o4.x + 4 * lane);
    ushort4 t01 = *(const ushort4*)(xtb + o4.y + 4 * lane);
    ushort4 t10 = *(const ushort4*)(xtb + o4.z + 4 * lane);
    ushort4 t11 = *(const ushort4*)(xtb + o4.w + 4 * lane);
    float r0 = w4.x * bf2f(t00.x) + w4.y * bf2f(t01.x) + w4.z * bf2f(t10.x) + w4.w * bf2f(t11.x);
    float r1 = w4.x * bf2f(t00.y) + w4.y * bf2f(t01.y) + w4.z * bf2f(t10.y) + w4.w * bf2f(t11.y);
    float r2 = w4.x * bf2f(t00.z) + w4.y * bf2f(t01.z) + w4.z * bf2f(t10.z) + w4.w * bf2f(t11.z);
    float r3 = w4.x * bf2f(t00.w) + w4.y * bf2f(t01.w) + w4.z * bf2f(t10.w) + w4.w * bf2f(t11.w);
    ushort4 o;
    o.x = f2bf(r0); o.y = f2bf(r1); o.z = f2bf(r2); o.w = f2bf(r3);
    *(ushort4*)(abase + (size_t)k * 8 * 512) = o;   // t advances by 8 per tap
  }
}

// ---------------- K3: main GEMM 128x64, LDS-free, coalesced frag loads ----------------
// a-frag: A2 + (mb*72 + t)*512 + row*32 + quad*8            (1KB/wave, contiguous)
// b-frag: WB2 + (t*16 + nj)*512 + quad*128 + row*8          (1KB/wave, contiguous)
// Register double-buffer, no barriers: 8 waves/CU interleave to hide L2 latency.
__global__ __launch_bounds__(256) void main_gemm(const unsigned short* __restrict__ A2,
                                                 const unsigned short* __restrict__ WB,
                                                 const float* __restrict__ bias,
                                                 float* __restrict__ out) {
  int tid = threadIdx.x;
  int lane = tid & 63, wv = tid >> 6;
  int m0 = blockIdx.x * 128;
  int n0 = blockIdx.y * 64;
  int wm = wv * 32;
  int row = lane & 15, quad = lane >> 4;
  f32x4 acc[2][4] = {};

  int mb0 = (m0 + wm) >> 4;          // wave's first 16-row block
  const unsigned short* aptr0 = A2 + (size_t)mb0 * 72 * 512 + row * 32 + quad * 8;
  const unsigned short* aptr1 = aptr0 + (size_t)72 * 512;
  const unsigned short* bptr = WB + (size_t)(blockIdx.y * 4) * 512 + quad * 128 + row * 8;

  bf16x8 a0c = *(const bf16x8*)(aptr0);
  bf16x8 a1c = *(const bf16x8*)(aptr1);
  bf16x8 bc0 = *(const bf16x8*)(bptr);
  bf16x8 bc1 = *(const bf16x8*)(bptr + 512);
  bf16x8 bc2 = *(const bf16x8*)(bptr + 1024);
  bf16x8 bc3 = *(const bf16x8*)(bptr + 1536);

  for (int t = 0; t < 72; ++t) {
    bf16x8 a0n, a1n, bn0, bn1, bn2, bn3;
    if (t < 71) {
      a0n = *(const bf16x8*)(aptr0 + (t + 1) * 512);
      a1n = *(const bf16x8*)(aptr1 + (t + 1) * 512);
      const unsigned short* bt = bptr + (size_t)(t + 1) * 8192;
      bn0 = *(const bf16x8*)(bt);
      bn1 = *(const bf16x8*)(bt + 512);
      bn2 = *(const bf16x8*)(bt + 1024);
      bn3 = *(const bf16x8*)(bt + 1536);
    }
    acc[0][0] = __builtin_amdgcn_mfma_f32_16x16x32_bf16(a0c, bc0, acc[0][0], 0, 0, 0);
    acc[0][1] = __builtin_amdgcn_mfma_f32_16x16x32_bf16(a0c, bc1, acc[0][1], 0, 0, 0);
    acc[0][2] = __builtin_amdgcn_mfma_f32_16x16x32_bf16(a0c, bc2, acc[0][2], 0, 0, 0);
    acc[0][3] = __builtin_amdgcn_mfma_f32_16x16x32_bf16(a0c, bc3, acc[0][3], 0, 0, 0);
    acc[1][0] = __builtin_amdgcn_mfma_f32_16x16x32_bf16(a1c, bc0, acc[1][0], 0, 0, 0);
    acc[1][1] = __builtin_amdgcn_mfma_f32_16x16x32_bf16(a1c, bc1, acc[1][1], 0, 0, 0);
    acc[1][2] = __builtin_amdgcn_mfma_f32_16x16x32_bf16(a1c, bc2, acc[1][2], 0, 0, 0);
    acc[1][3] = __builtin_amdgcn_mfma_f32_16x16x32_bf16(a1c, bc3, acc[1][3], 0, 0, 0);
    a0c = a0n; a1c = a1n;
    bc0 = bn0; bc1 = bn1; bc2 = bn2; bc3 = bn3;
  }

  int b = m0 >> 12, hw0 = m0 & 4095;
#pragma unroll
  for (int j = 0; j < 4; ++j) {
    int o = n0 + j * 16 + row;
    float bo = bias[o];
#pragma unroll
    for (int i = 0; i < 2; ++i) {
      int hw = hw0 + wm + i * 16 + quad * 4;
      float4 v;
      v.x = acc[i][j][0] + bo;
      v.y = acc[i][j][1] + bo;
      v.z = acc[i][j][2] + bo;
      v.w = acc[i][j][3] + bo;
      *(float4*)(out + (((size_t)(b * COUT + o)) << 12) + hw) = v;
    }
  }
}

// ---------------- launch ----------------
extern "C" void kernel_launch(void* const* d_in, const int* in_sizes, int n_in,
                              void* d_out, int out_size, void* d_ws, size_t ws_size,
                              hipStream_t stream) {
  const float* x        = (const float*)d_in[0];
  const float* weight   = (const float*)d_in[1];
  const float* bias     = (const float*)d_in[2];
  const float* p_weight = (const float*)d_in[3];
  const float* p_bias   = (const float*)d_in[4];
  float* out = (float*)d_out;
  char* ws = (char*)d_ws;

  // workspace layout (bytes); total ~102 MB of 256 MiB
  const size_t OFF_XT   = 0;                          //  8,388,608  bf16 NHWC x
  const size_t OFF_WB   = OFF_XT + 8388608;           //  1,179,648  bf16 WB2
  const size_t OFF_PW   = OFF_WB + 1179648;           //    147,456  bf16
  const size_t OFF_P    = OFF_PW + 147456;            // 16,777,216  fp32 partials
  const size_t OFF_ZP   = OFF_P + 16777216;           //      8,192  zeropage
  const size_t OFF_A    = OFF_ZP + 8192;              // 75,497,472  bf16 A2

  unsigned short* xt    = (unsigned short*)(ws + OFF_XT);
  unsigned short* WB    = (unsigned short*)(ws + OFF_WB);
  unsigned short* PWs   = (unsigned short*)(ws + OFF_PW);
  float* Pbuf           = (float*)(ws + OFF_P);
  unsigned short* zerop = (unsigned short*)(ws + OFF_ZP);
  unsigned short* Amat  = (unsigned short*)(ws + OFF_A);

  prep_and_transpose<<<4096 + 2592, 256, 0, stream>>>(x, weight, p_weight, xt, WB, PWs, zerop);
  offset_conv_sk<<<dim3(MTOT / 64, SPLITK), 256, 0, stream>>>(xt, PWs, zerop, Pbuf);
  sample9<<<MTOT / 4, 256, 0, stream>>>(xt, Pbuf, p_bias, Amat);
  main_gemm<<<dim3(MTOT / 128, COUT / 64), 256, 0, stream>>>(Amat, WB, bias, out);
}

// Round 12
// 149.844 us; speedup vs baseline: 1.1294x; 1.0031x over previous
//
#include <hip/hip_runtime.h>
#include <stdint.h>

// DCNv2 forward, MI355X — R11: LDS-free main GEMM, ping-pong register double
// buffer with hand-unroll-by-2 (R10 had 48 v_mov/iter from rotating copies ->
// VALUBusy 44%; now zero copies, branch-free body, last two tiles peeled).
//  K0 prep_and_transpose : x NCHW fp32 -> xt NHWC bf16; W -> WB2 bf16 in
//     [t][j][quad][row][8] (1KB contiguous per B-fragment); PWs; zeropage.
//  K1 offset_conv_sk : split-K (S=8) implicit-im2col bf16 MFMA conv, BM=64,
//     XCD-swizzled; A staged via global_load_lds from bf16 xt.
//  K2 sample9 : one wave per m, 9 taps; inline finalize; writes A2 in
//     [m/16][t][row][quad][8] (1KB contiguous per A-fragment).
//  K3 main_gemm : 128x64, NO LDS, two named frag register sets, unroll-2
//     ping-pong (load set covered by the other set's 8 MFMAs), no barriers.
// Workspace ~102 MB of 256 MiB.

#define CIN 256
#define COUT 256
#define HWS 4096      // H*W
#define MTOT 16384    // B*H*W
#define KTOT 2304     // CIN*9
#define SPLITK 8

typedef __attribute__((ext_vector_type(8))) short bf16x8;
typedef __attribute__((ext_vector_type(4))) float f32x4;

__device__ __forceinline__ unsigned short f2bf(float f) {
  unsigned int u = __float_as_uint(f);
  unsigned int r = (u + 0x7fffu + ((u >> 16) & 1u)) >> 16;
  return (unsigned short)r;
}
__device__ __forceinline__ float bf2f(unsigned short u) {
  return __uint_as_float(((unsigned int)u) << 16);
}

__device__ __forceinline__ void gload_lds16(const void* g, void* l) {
  __builtin_amdgcn_global_load_lds((const __attribute__((address_space(1))) void*)g,
                                   (__attribute__((address_space(3))) void*)l, 16, 0, 0);
}

// ---------------- K0: fused transpose + weight prep (WB2 frag-block order) ----------------
__global__ __launch_bounds__(256) void prep_and_transpose(const float* __restrict__ x,
                                                          const float* __restrict__ w,
                                                          const float* __restrict__ pw,
                                                          unsigned short* __restrict__ xt,
                                                          unsigned short* __restrict__ WB,
                                                          unsigned short* __restrict__ PWs,
                                                          unsigned short* __restrict__ zerop) {
  __shared__ float tile[32][33];
  int bid = blockIdx.x;
  if (bid < 4096) {
    int b = bid >> 10;
    int rest = bid & 1023;
    int hw0 = (rest & 127) * 32;
    int c0 = ((rest >> 7) & 7) * 32;
    int tx = threadIdx.x & 31, ty = threadIdx.x >> 5;
    for (int i = ty; i < 32; i += 8)
      tile[i][tx] = x[(size_t)(b * CIN + c0 + i) * HWS + hw0 + tx];
    __syncthreads();
    for (int r = ty; r < 32; r += 8)
      xt[(size_t)(b * HWS + hw0 + r) * CIN + c0 + tx] = f2bf(tile[tx][r]);
  } else {
    int idx = (bid - 4096) * 256 + threadIdx.x;
    if (idx < 512)
      *(uint4*)(zerop + idx * 8) = make_uint4(0, 0, 0, 0);
    if (idx < KTOT * COUT) {
      // WB2[t][j][quad][row][8]: f = (((t*16+j)*4+quad)*16+row)*8+e
      int f = idx;
      int e = f & 7;
      int row = (f >> 3) & 15;
      int quad = (f >> 7) & 3;
      int j = (f >> 9) & 15;
      int t = f >> 13;                 // 0..71
      int kk = t * 32 + quad * 8 + e;
      int o = j * 16 + row;
      int k = kk >> 8, c = kk & 255;
      WB[f] = f2bf(w[o * KTOT + c * 9 + k]);
    } else {
      int f2 = idx - KTOT * COUT;   // < 2304*32
      int t_ = f2 & 7;
      int rest = f2 >> 3;
      int j = rest & 31;
      int kk = (rest >> 5) * 8 + t_;
      int k = kk >> 8, c = kk & 255;
      float v = (j < 27) ? pw[j * KTOT + c * 9 + k] : 0.0f;
      PWs[f2] = f2bf(v);
    }
  }
}

// ---------------- K1: offset conv, split-K, BM=64 ----------------
__global__ __launch_bounds__(256) void offset_conv_sk(const unsigned short* __restrict__ xt,
                                                      const unsigned short* __restrict__ PWs,
                                                      const unsigned short* __restrict__ zerop,
                                                      float* __restrict__ Pbuf) {
  __shared__ unsigned short Al[64 * 32];   // 4 KB
  __shared__ unsigned short Bl[1024];      // 2 KB
  int tid = threadIdx.x;
  int lane = tid & 63, wv = tid >> 6;
  int mt = (blockIdx.x & 7) * 32 + (blockIdx.x >> 3);   // XCD swizzle
  int m0 = mt * 64;
  int s = blockIdx.y;
  int b = m0 >> 12;
  int hw0 = m0 & 4095;
  f32x4 acc[2] = {};

  for (int tt = 0; tt < 72 / SPLITK; ++tt) {
    int t = s * (72 / SPLITK) + tt;
    int k = t >> 3, c0 = (t & 7) * 32;
    int dyk = k / 3 - 1;
    int dxk = k % 3 - 1;
    __syncthreads();
    if (tid < 128)
      gload_lds16(PWs + (size_t)t * 1024 + tid * 8, &Bl[tid * 8]);
    {
      int r = tid >> 2;
      int hw = hw0 + r;
      int h = hw >> 6, wwp = hw & 63;
      int y = h + dyk, xx = wwp + dxk;
      bool valid = ((unsigned)y < 64u) && ((unsigned)xx < 64u);
      const unsigned short* src = valid
          ? xt + ((size_t)((b << 12) + (y << 6) + xx) << 8) + c0 + (tid & 3) * 8
          : zerop;
      gload_lds16(src, &Al[tid * 8]);
    }
    __syncthreads();
    int row = lane & 15, quad = lane >> 4;
    bf16x8 af = *(const bf16x8*)&Al[(wv * 16 + row) * 32 + quad * 8];
    for (int j = 0; j < 2; ++j) {
      bf16x8 bfr = *(const bf16x8*)&Bl[(quad * 32 + j * 16 + row) * 8];
      acc[j] = __builtin_amdgcn_mfma_f32_16x16x32_bf16(af, bfr, acc[j], 0, 0, 0);
    }
  }

  int row = lane & 15, quad = lane >> 4;
  for (int j = 0; j < 2; ++j) {
    int n = j * 16 + row;
    for (int r_ = 0; r_ < 4; ++r_) {
      int m = m0 + wv * 16 + quad * 4 + r_;
      Pbuf[((size_t)s * MTOT + m) * 32 + n] = acc[j][r_];
    }
  }
}

// ---------------- K2: sample9, writes A2 in fragment-block order ----------------
__global__ __launch_bounds__(256) void sample9(const unsigned short* __restrict__ xt,
                                               const float* __restrict__ Pbuf,
                                               const float* __restrict__ p_bias,
                                               unsigned short* __restrict__ A) {
  __shared__ int4 dI[4][9];
  __shared__ float4 dW[4][9];
  int tid = threadIdx.x;
  int reg = blockIdx.x & 7;                     // XCD region (matches K1)
  int mb = reg * 2048 + (blockIdx.x >> 3) * 4;  // base m of this block

  if (tid < 36) {
    int lm = tid / 9, k = tid - lm * 9;
    int m = mb + lm;
    float dy = p_bias[2 * k];
    float dx = p_bias[2 * k + 1];
    float mv = p_bias[18 + k];
#pragma unroll
    for (int s = 0; s < SPLITK; ++s) {
      const float* p = Pbuf + ((size_t)s * MTOT + m) * 32;
      dy += p[2 * k];
      dx += p[2 * k + 1];
      mv += p[18 + k];
    }
    float mk = 1.0f / (1.0f + __expf(-mv));

    int hw = m & 4095, h = hw >> 6, ww = hw & 63;
    float py = (float)(h - 1 + k / 3) + dy;
    float px = (float)(ww - 1 + k % 3) + dx;
    float y0f = floorf(py), x0f = floorf(px);
    float ay = py - y0f, ax = px - x0f;
    int y0 = (int)y0f, x0 = (int)x0f;

    float w00 = (1.f - ay) * (1.f - ax) * mk;
    float w01 = (1.f - ay) * ax * mk;
    float w10 = ay * (1.f - ax) * mk;
    float w11 = ay * ax * mk;

    float vy0 = ((unsigned)y0 < 64u) ? 1.f : 0.f;
    float vy1 = ((unsigned)(y0 + 1) < 64u) ? 1.f : 0.f;
    float vx0 = ((unsigned)x0 < 64u) ? 1.f : 0.f;
    float vx1 = ((unsigned)(x0 + 1) < 64u) ? 1.f : 0.f;
    w00 *= vy0 * vx0; w01 *= vy0 * vx1; w10 *= vy1 * vx0; w11 *= vy1 * vx1;

    int yc0 = min(max(y0, 0), 63), yc1 = min(max(y0 + 1, 0), 63);
    int xc0 = min(max(x0, 0), 63), xc1 = min(max(x0 + 1, 0), 63);

    dI[lm][k] = make_int4((yc0 * 64 + xc0) * 256, (yc0 * 64 + xc1) * 256,
                          (yc1 * 64 + xc0) * 256, (yc1 * 64 + xc1) * 256);
    dW[lm][k] = make_float4(w00, w01, w10, w11);
  }
  __syncthreads();

  int wv = tid >> 6, lane = tid & 63;
  int m = mb + wv;
  int b = m >> 12;
  const unsigned short* xtb = xt + (((size_t)b << 12) << 8);
  // fragment-order base: block (m>>4), sub-t (lane>>3), row (m&15), quad, e0
  unsigned short* abase = A + (((size_t)(m >> 4) * 72 + (lane >> 3)) * 16 + (m & 15)) * 32
                            + ((lane >> 1) & 3) * 8 + (lane & 1) * 4;

#pragma unroll
  for (int k = 0; k < 9; ++k) {
    int4 o4 = dI[wv][k];       // LDS broadcast — free
    float4 w4 = dW[wv][k];
    ushort4 t00 = *(const ushort4*)(xtb + o4.x + 4 * lane);
    ushort4 t01 = *(const ushort4*)(xtb + o4.y + 4 * lane);
    ushort4 t10 = *(const ushort4*)(xtb + o4.z + 4 * lane);
    ushort4 t11 = *(const ushort4*)(xtb + o4.w + 4 * lane);
    float r0 = w4.x * bf2f(t00.x) + w4.y * bf2f(t01.x) + w4.z * bf2f(t10.x) + w4.w * bf2f(t11.x);
    float r1 = w4.x * bf2f(t00.y) + w4.y * bf2f(t01.y) + w4.z * bf2f(t10.y) + w4.w * bf2f(t11.y);
    float r2 = w4.x * bf2f(t00.z) + w4.y * bf2f(t01.z) + w4.z * bf2f(t10.z) + w4.w * bf2f(t11.z);
    float r3 = w4.x * bf2f(t00.w) + w4.y * bf2f(t01.w) + w4.z * bf2f(t10.w) + w4.w * bf2f(t11.w);
    ushort4 o;
    o.x = f2bf(r0); o.y = f2bf(r1); o.z = f2bf(r2); o.w = f2bf(r3);
    *(ushort4*)(abase + (size_t)k * 8 * 512) = o;   // t advances by 8 per tap
  }
}

// ---------------- K3: main GEMM 128x64, LDS-free, ping-pong unroll-2 ----------------
// a-frag: A2 + (mb*72 + t)*512 + row*32 + quad*8   (1KB/wave contiguous)
// b-frag: WB2 + t*8192 + nj*512 + quad*128 + row*8 (1KB/wave contiguous)
// Two named register sets; compute(set) then reload(set) — loads covered by
// the other set's 8 MFMAs; last two tiles peeled so the body is branch-free.
__global__ __launch_bounds__(256) void main_gemm(const unsigned short* __restrict__ A2,
                                                 const unsigned short* __restrict__ WB,
                                                 const float* __restrict__ bias,
                                                 float* __restrict__ out) {
  int tid = threadIdx.x;
  int lane = tid & 63, wv = tid >> 6;
  int m0 = blockIdx.x * 128;
  int n0 = blockIdx.y * 64;
  int wm = wv * 32;
  int row = lane & 15, quad = lane >> 4;
  f32x4 acc[2][4] = {};

  int mb0 = (m0 + wm) >> 4;
  const unsigned short* ap0 = A2 + (size_t)mb0 * 72 * 512 + row * 32 + quad * 8;
  const unsigned short* ap1 = ap0 + (size_t)72 * 512;
  const unsigned short* bp = WB + (size_t)(blockIdx.y * 4) * 512 + quad * 128 + row * 8;
  // per-tile strides: A 512 ushorts, B 8192 ushorts

  // set X = tile 0, set Y = tile 1
  bf16x8 xa0 = *(const bf16x8*)(ap0);
  bf16x8 xa1 = *(const bf16x8*)(ap1);
  bf16x8 xb0 = *(const bf16x8*)(bp);
  bf16x8 xb1 = *(const bf16x8*)(bp + 512);
  bf16x8 xb2 = *(const bf16x8*)(bp + 1024);
  bf16x8 xb3 = *(const bf16x8*)(bp + 1536);
  bf16x8 ya0 = *(const bf16x8*)(ap0 + 512);
  bf16x8 ya1 = *(const bf16x8*)(ap1 + 512);
  bf16x8 yb0 = *(const bf16x8*)(bp + 8192);
  bf16x8 yb1 = *(const bf16x8*)(bp + 8192 + 512);
  bf16x8 yb2 = *(const bf16x8*)(bp + 8192 + 1024);
  bf16x8 yb3 = *(const bf16x8*)(bp + 8192 + 1536);

#pragma unroll 1
  for (int t = 0; t < 70; t += 2) {
    // compute tile t from set X
    acc[0][0] = __builtin_amdgcn_mfma_f32_16x16x32_bf16(xa0, xb0, acc[0][0], 0, 0, 0);
    acc[0][1] = __builtin_amdgcn_mfma_f32_16x16x32_bf16(xa0, xb1, acc[0][1], 0, 0, 0);
    acc[0][2] = __builtin_amdgcn_mfma_f32_16x16x32_bf16(xa0, xb2, acc[0][2], 0, 0, 0);
    acc[0][3] = __builtin_amdgcn_mfma_f32_16x16x32_bf16(xa0, xb3, acc[0][3], 0, 0, 0);
    acc[1][0] = __builtin_amdgcn_mfma_f32_16x16x32_bf16(xa1, xb0, acc[1][0], 0, 0, 0);
    acc[1][1] = __builtin_amdgcn_mfma_f32_16x16x32_bf16(xa1, xb1, acc[1][1], 0, 0, 0);
    acc[1][2] = __builtin_amdgcn_mfma_f32_16x16x32_bf16(xa1, xb2, acc[1][2], 0, 0, 0);
    acc[1][3] = __builtin_amdgcn_mfma_f32_16x16x32_bf16(xa1, xb3, acc[1][3], 0, 0, 0);
    // reload set X with tile t+2 (covered by set-Y computes below)
    {
      const unsigned short* a0 = ap0 + (size_t)(t + 2) * 512;
      const unsigned short* a1 = ap1 + (size_t)(t + 2) * 512;
      const unsigned short* bt = bp + (size_t)(t + 2) * 8192;
      xa0 = *(const bf16x8*)(a0);
      xa1 = *(const bf16x8*)(a1);
      xb0 = *(const bf16x8*)(bt);
      xb1 = *(const bf16x8*)(bt + 512);
      xb2 = *(const bf16x8*)(bt + 1024);
      xb3 = *(const bf16x8*)(bt + 1536);
    }
    // compute tile t+1 from set Y
    acc[0][0] = __builtin_amdgcn_mfma_f32_16x16x32_bf16(ya0, yb0, acc[0][0], 0, 0, 0);
    acc[0][1] = __builtin_amdgcn_mfma_f32_16x16x32_bf16(ya0, yb1, acc[0][1], 0, 0, 0);
    acc[0][2] = __builtin_amdgcn_mfma_f32_16x16x32_bf16(ya0, yb2, acc[0][2], 0, 0, 0);
    acc[0][3] = __builtin_amdgcn_mfma_f32_16x16x32_bf16(ya0, yb3, acc[0][3], 0, 0, 0);
    acc[1][0] = __builtin_amdgcn_mfma_f32_16x16x32_bf16(ya1, yb0, acc[1][0], 0, 0, 0);
    acc[1][1] = __builtin_amdgcn_mfma_f32_16x16x32_bf16(ya1, yb1, acc[1][1], 0, 0, 0);
    acc[1][2] = __builtin_amdgcn_mfma_f32_16x16x32_bf16(ya1, yb2, acc[1][2], 0, 0, 0);
    acc[1][3] = __builtin_amdgcn_mfma_f32_16x16x32_bf16(ya1, yb3, acc[1][3], 0, 0, 0);
    // reload set Y with tile t+3
    {
      const unsigned short* a0 = ap0 + (size_t)(t + 3) * 512;
      const unsigned short* a1 = ap1 + (size_t)(t + 3) * 512;
      const unsigned short* bt = bp + (size_t)(t + 3) * 8192;
      ya0 = *(const bf16x8*)(a0);
      ya1 = *(const bf16x8*)(a1);
      yb0 = *(const bf16x8*)(bt);
      yb1 = *(const bf16x8*)(bt + 512);
      yb2 = *(const bf16x8*)(bt + 1024);
      yb3 = *(const bf16x8*)(bt + 1536);
    }
  }
  // peeled tiles 70 (X) and 71 (Y)
  acc[0][0] = __builtin_amdgcn_mfma_f32_16x16x32_bf16(xa0, xb0, acc[0][0], 0, 0, 0);
  acc[0][1] = __builtin_amdgcn_mfma_f32_16x16x32_bf16(xa0, xb1, acc[0][1], 0, 0, 0);
  acc[0][2] = __builtin_amdgcn_mfma_f32_16x16x32_bf16(xa0, xb2, acc[0][2], 0, 0, 0);
  acc[0][3] = __builtin_amdgcn_mfma_f32_16x16x32_bf16(xa0, xb3, acc[0][3], 0, 0, 0);
  acc[1][0] = __builtin_amdgcn_mfma_f32_16x16x32_bf16(xa1, xb0, acc[1][0], 0, 0, 0);
  acc[1][1] = __builtin_amdgcn_mfma_f32_16x16x32_bf16(xa1, xb1, acc[1][1], 0, 0, 0);
  acc[1][2] = __builtin_amdgcn_mfma_f32_16x16x32_bf16(xa1, xb2, acc[1][2], 0, 0, 0);
  acc[1][3] = __builtin_amdgcn_mfma_f32_16x16x32_bf16(xa1, xb3, acc[1][3], 0, 0, 0);
  acc[0][0] = __builtin_amdgcn_mfma_f32_16x16x32_bf16(ya0, yb0, acc[0][0], 0, 0, 0);
  acc[0][1] = __builtin_amdgcn_mfma_f32_16x16x32_bf16(ya0, yb1, acc[0][1], 0, 0, 0);
  acc[0][2] = __builtin_amdgcn_mfma_f32_16x16x32_bf16(ya0, yb2, acc[0][2], 0, 0, 0);
  acc[0][3] = __builtin_amdgcn_mfma_f32_16x16x32_bf16(ya0, yb3, acc[0][3], 0, 0, 0);
  acc[1][0] = __builtin_amdgcn_mfma_f32_16x16x32_bf16(ya1, yb0, acc[1][0], 0, 0, 0);
  acc[1][1] = __builtin_amdgcn_mfma_f32_16x16x32_bf16(ya1, yb1, acc[1][1], 0, 0, 0);
  acc[1][2] = __builtin_amdgcn_mfma_f32_16x16x32_bf16(ya1, yb2, acc[1][2], 0, 0, 0);
  acc[1][3] = __builtin_amdgcn_mfma_f32_16x16x32_bf16(ya1, yb3, acc[1][3], 0, 0, 0);

  int b = m0 >> 12, hw0 = m0 & 4095;
#pragma unroll
  for (int j = 0; j < 4; ++j) {
    int o = n0 + j * 16 + row;
    float bo = bias[o];
#pragma unroll
    for (int i = 0; i < 2; ++i) {
      int hw = hw0 + wm + i * 16 + quad * 4;
      float4 v;
      v.x = acc[i][j][0] + bo;
      v.y = acc[i][j][1] + bo;
      v.z = acc[i][j][2] + bo;
      v.w = acc[i][j][3] + bo;
      *(float4*)(out + (((size_t)(b * COUT + o)) << 12) + hw) = v;
    }
  }
}

// ---------------- launch ----------------
extern "C" void kernel_launch(void* const* d_in, const int* in_sizes, int n_in,
                              void* d_out, int out_size, void* d_ws, size_t ws_size,
                              hipStream_t stream) {
  const float* x        = (const float*)d_in[0];
  const float* weight   = (const float*)d_in[1];
  const float* bias     = (const float*)d_in[2];
  const float* p_weight = (const float*)d_in[3];
  const float* p_bias   = (const float*)d_in[4];
  float* out = (float*)d_out;
  char* ws = (char*)d_ws;

  // workspace layout (bytes); total ~102 MB of 256 MiB
  const size_t OFF_XT   = 0;                          //  8,388,608  bf16 NHWC x
  const size_t OFF_WB   = OFF_XT + 8388608;           //  1,179,648  bf16 WB2
  const size_t OFF_PW   = OFF_WB + 1179648;           //    147,456  bf16
  const size_t OFF_P    = OFF_PW + 147456;            // 16,777,216  fp32 partials
  const size_t OFF_ZP   = OFF_P + 16777216;           //      8,192  zeropage
  const size_t OFF_A    = OFF_ZP + 8192;              // 75,497,472  bf16 A2

  unsigned short* xt    = (unsigned short*)(ws + OFF_XT);
  unsigned short* WB    = (unsigned short*)(ws + OFF_WB);
  unsigned short* PWs   = (unsigned short*)(ws + OFF_PW);
  float* Pbuf           = (float*)(ws + OFF_P);
  unsigned short* zerop = (unsigned short*)(ws + OFF_ZP);
  unsigned short* Amat  = (unsigned short*)(ws + OFF_A);

  prep_and_transpose<<<4096 + 2592, 256, 0, stream>>>(x, weight, p_weight, xt, WB, PWs, zerop);
  offset_conv_sk<<<dim3(MTOT / 64, SPLITK), 256, 0, stream>>>(xt, PWs, zerop, Pbuf);
  sample9<<<MTOT / 4, 256, 0, stream>>>(xt, Pbuf, p_bias, Amat);
  main_gemm<<<dim3(MTOT / 128, COUT / 64), 256, 0, stream>>>(Amat, WB, bias, out);
}

// Round 13
// 148.230 us; speedup vs baseline: 1.1417x; 1.0109x over previous
//
#include <hip/hip_runtime.h>
#include <stdint.h>

// DCNv2 forward, MI355X — R12: main_gemm latency attack v3.
//  Diagnosis (R11): FETCH 41.5MB => A2 reads miss L2 (75.5MB intermediate),
//  ~500-900cyc latency vs ~120cyc pipeline coverage. Fix:
//   (1) XCD-affinity grid swizzle: 4 n-blocks of an m-tile share an XCD and
//       dispatch window (bids differ by 8) -> 1 deep miss + 3 L2 hits; XCD
//       also matches sample9's producer region.
//   (2) depth-4 register pipeline (4 named sets, branch-free, 4-tile epilogue).
//  K0 prep_and_transpose, K1 offset_conv_sk, K2 sample9: unchanged from R11.
// Workspace ~102 MB of 256 MiB.

#define CIN 256
#define COUT 256
#define HWS 4096      // H*W
#define MTOT 16384    // B*H*W
#define KTOT 2304     // CIN*9
#define SPLITK 8

typedef __attribute__((ext_vector_type(8))) short bf16x8;
typedef __attribute__((ext_vector_type(4))) float f32x4;

__device__ __forceinline__ unsigned short f2bf(float f) {
  unsigned int u = __float_as_uint(f);
  unsigned int r = (u + 0x7fffu + ((u >> 16) & 1u)) >> 16;
  return (unsigned short)r;
}
__device__ __forceinline__ float bf2f(unsigned short u) {
  return __uint_as_float(((unsigned int)u) << 16);
}

__device__ __forceinline__ void gload_lds16(const void* g, void* l) {
  __builtin_amdgcn_global_load_lds((const __attribute__((address_space(1))) void*)g,
                                   (__attribute__((address_space(3))) void*)l, 16, 0, 0);
}

// ---------------- K0: fused transpose + weight prep (WB2 frag-block order) ----------------
__global__ __launch_bounds__(256) void prep_and_transpose(const float* __restrict__ x,
                                                          const float* __restrict__ w,
                                                          const float* __restrict__ pw,
                                                          unsigned short* __restrict__ xt,
                                                          unsigned short* __restrict__ WB,
                                                          unsigned short* __restrict__ PWs,
                                                          unsigned short* __restrict__ zerop) {
  __shared__ float tile[32][33];
  int bid = blockIdx.x;
  if (bid < 4096) {
    int b = bid >> 10;
    int rest = bid & 1023;
    int hw0 = (rest & 127) * 32;
    int c0 = ((rest >> 7) & 7) * 32;
    int tx = threadIdx.x & 31, ty = threadIdx.x >> 5;
    for (int i = ty; i < 32; i += 8)
      tile[i][tx] = x[(size_t)(b * CIN + c0 + i) * HWS + hw0 + tx];
    __syncthreads();
    for (int r = ty; r < 32; r += 8)
      xt[(size_t)(b * HWS + hw0 + r) * CIN + c0 + tx] = f2bf(tile[tx][r]);
  } else {
    int idx = (bid - 4096) * 256 + threadIdx.x;
    if (idx < 512)
      *(uint4*)(zerop + idx * 8) = make_uint4(0, 0, 0, 0);
    if (idx < KTOT * COUT) {
      // WB2[t][j][quad][row][8]: f = (((t*16+j)*4+quad)*16+row)*8+e
      int f = idx;
      int e = f & 7;
      int row = (f >> 3) & 15;
      int quad = (f >> 7) & 3;
      int j = (f >> 9) & 15;
      int t = f >> 13;                 // 0..71
      int kk = t * 32 + quad * 8 + e;
      int o = j * 16 + row;
      int k = kk >> 8, c = kk & 255;
      WB[f] = f2bf(w[o * KTOT + c * 9 + k]);
    } else {
      int f2 = idx - KTOT * COUT;   // < 2304*32
      int t_ = f2 & 7;
      int rest = f2 >> 3;
      int j = rest & 31;
      int kk = (rest >> 5) * 8 + t_;
      int k = kk >> 8, c = kk & 255;
      float v = (j < 27) ? pw[j * KTOT + c * 9 + k] : 0.0f;
      PWs[f2] = f2bf(v);
    }
  }
}

// ---------------- K1: offset conv, split-K, BM=64 ----------------
__global__ __launch_bounds__(256) void offset_conv_sk(const unsigned short* __restrict__ xt,
                                                      const unsigned short* __restrict__ PWs,
                                                      const unsigned short* __restrict__ zerop,
                                                      float* __restrict__ Pbuf) {
  __shared__ unsigned short Al[64 * 32];   // 4 KB
  __shared__ unsigned short Bl[1024];      // 2 KB
  int tid = threadIdx.x;
  int lane = tid & 63, wv = tid >> 6;
  int mt = (blockIdx.x & 7) * 32 + (blockIdx.x >> 3);   // XCD swizzle
  int m0 = mt * 64;
  int s = blockIdx.y;
  int b = m0 >> 12;
  int hw0 = m0 & 4095;
  f32x4 acc[2] = {};

  for (int tt = 0; tt < 72 / SPLITK; ++tt) {
    int t = s * (72 / SPLITK) + tt;
    int k = t >> 3, c0 = (t & 7) * 32;
    int dyk = k / 3 - 1;
    int dxk = k % 3 - 1;
    __syncthreads();
    if (tid < 128)
      gload_lds16(PWs + (size_t)t * 1024 + tid * 8, &Bl[tid * 8]);
    {
      int r = tid >> 2;
      int hw = hw0 + r;
      int h = hw >> 6, wwp = hw & 63;
      int y = h + dyk, xx = wwp + dxk;
      bool valid = ((unsigned)y < 64u) && ((unsigned)xx < 64u);
      const unsigned short* src = valid
          ? xt + ((size_t)((b << 12) + (y << 6) + xx) << 8) + c0 + (tid & 3) * 8
          : zerop;
      gload_lds16(src, &Al[tid * 8]);
    }
    __syncthreads();
    int row = lane & 15, quad = lane >> 4;
    bf16x8 af = *(const bf16x8*)&Al[(wv * 16 + row) * 32 + quad * 8];
    for (int j = 0; j < 2; ++j) {
      bf16x8 bfr = *(const bf16x8*)&Bl[(quad * 32 + j * 16 + row) * 8];
      acc[j] = __builtin_amdgcn_mfma_f32_16x16x32_bf16(af, bfr, acc[j], 0, 0, 0);
    }
  }

  int row = lane & 15, quad = lane >> 4;
  for (int j = 0; j < 2; ++j) {
    int n = j * 16 + row;
    for (int r_ = 0; r_ < 4; ++r_) {
      int m = m0 + wv * 16 + quad * 4 + r_;
      Pbuf[((size_t)s * MTOT + m) * 32 + n] = acc[j][r_];
    }
  }
}

// ---------------- K2: sample9, writes A2 in fragment-block order ----------------
__global__ __launch_bounds__(256) void sample9(const unsigned short* __restrict__ xt,
                                               const float* __restrict__ Pbuf,
                                               const float* __restrict__ p_bias,
                                               unsigned short* __restrict__ A) {
  __shared__ int4 dI[4][9];
  __shared__ float4 dW[4][9];
  int tid = threadIdx.x;
  int reg = blockIdx.x & 7;                     // XCD region (matches K1)
  int mb = reg * 2048 + (blockIdx.x >> 3) * 4;  // base m of this block

  if (tid < 36) {
    int lm = tid / 9, k = tid - lm * 9;
    int m = mb + lm;
    float dy = p_bias[2 * k];
    float dx = p_bias[2 * k + 1];
    float mv = p_bias[18 + k];
#pragma unroll
    for (int s = 0; s < SPLITK; ++s) {
      const float* p = Pbuf + ((size_t)s * MTOT + m) * 32;
      dy += p[2 * k];
      dx += p[2 * k + 1];
      mv += p[18 + k];
    }
    float mk = 1.0f / (1.0f + __expf(-mv));

    int hw = m & 4095, h = hw >> 6, ww = hw & 63;
    float py = (float)(h - 1 + k / 3) + dy;
    float px = (float)(ww - 1 + k % 3) + dx;
    float y0f = floorf(py), x0f = floorf(px);
    float ay = py - y0f, ax = px - x0f;
    int y0 = (int)y0f, x0 = (int)x0f;

    float w00 = (1.f - ay) * (1.f - ax) * mk;
    float w01 = (1.f - ay) * ax * mk;
    float w10 = ay * (1.f - ax) * mk;
    float w11 = ay * ax * mk;

    float vy0 = ((unsigned)y0 < 64u) ? 1.f : 0.f;
    float vy1 = ((unsigned)(y0 + 1) < 64u) ? 1.f : 0.f;
    float vx0 = ((unsigned)x0 < 64u) ? 1.f : 0.f;
    float vx1 = ((unsigned)(x0 + 1) < 64u) ? 1.f : 0.f;
    w00 *= vy0 * vx0; w01 *= vy0 * vx1; w10 *= vy1 * vx0; w11 *= vy1 * vx1;

    int yc0 = min(max(y0, 0), 63), yc1 = min(max(y0 + 1, 0), 63);
    int xc0 = min(max(x0, 0), 63), xc1 = min(max(x0 + 1, 0), 63);

    dI[lm][k] = make_int4((yc0 * 64 + xc0) * 256, (yc0 * 64 + xc1) * 256,
                          (yc1 * 64 + xc0) * 256, (yc1 * 64 + xc1) * 256);
    dW[lm][k] = make_float4(w00, w01, w10, w11);
  }
  __syncthreads();

  int wv = tid >> 6, lane = tid & 63;
  int m = mb + wv;
  int b = m >> 12;
  const unsigned short* xtb = xt + (((size_t)b << 12) << 8);
  // fragment-order base: block (m>>4), sub-t (lane>>3), row (m&15), quad, e0
  unsigned short* abase = A + (((size_t)(m >> 4) * 72 + (lane >> 3)) * 16 + (m & 15)) * 32
                            + ((lane >> 1) & 3) * 8 + (lane & 1) * 4;

#pragma unroll
  for (int k = 0; k < 9; ++k) {
    int4 o4 = dI[wv][k];       // LDS broadcast — free
    float4 w4 = dW[wv][k];
    ushort4 t00 = *(const ushort4*)(xtb + o4.x + 4 * lane);
    ushort4 t01 = *(const ushort4*)(xtb + o4.y + 4 * lane);
    ushort4 t10 = *(const ushort4*)(xtb + o4.z + 4 * lane);
    ushort4 t11 = *(const ushort4*)(xtb + o4.w + 4 * lane);
    float r0 = w4.x * bf2f(t00.x) + w4.y * bf2f(t01.x) + w4.z * bf2f(t10.x) + w4.w * bf2f(t11.x);
    float r1 = w4.x * bf2f(t00.y) + w4.y * bf2f(t01.y) + w4.z * bf2f(t10.y) + w4.w * bf2f(t11.y);
    float r2 = w4.x * bf2f(t00.z) + w4.y * bf2f(t01.z) + w4.z * bf2f(t10.z) + w4.w * bf2f(t11.z);
    float r3 = w4.x * bf2f(t00.w) + w4.y * bf2f(t01.w) + w4.z * bf2f(t10.w) + w4.w * bf2f(t11.w);
    ushort4 o;
    o.x = f2bf(r0); o.y = f2bf(r1); o.z = f2bf(r2); o.w = f2bf(r3);
    *(ushort4*)(abase + (size_t)k * 8 * 512) = o;   // t advances by 8 per tap
  }
}

// ---------------- K3: main GEMM 128x64, LDS-free, depth-4 pipeline + XCD swizzle ----------------
#define LOADSET(SA0, SA1, SB0, SB1, SB2, SB3, TT)                         \
  {                                                                       \
    const unsigned short* a0_ = ap0 + (size_t)(TT) * 512;                 \
    const unsigned short* a1_ = ap1 + (size_t)(TT) * 512;                 \
    const unsigned short* bt_ = bp + (size_t)(TT) * 8192;                 \
    SA0 = *(const bf16x8*)(a0_);                                          \
    SA1 = *(const bf16x8*)(a1_);                                          \
    SB0 = *(const bf16x8*)(bt_);                                          \
    SB1 = *(const bf16x8*)(bt_ + 512);                                    \
    SB2 = *(const bf16x8*)(bt_ + 1024);                                   \
    SB3 = *(const bf16x8*)(bt_ + 1536);                                   \
  }

#define COMPUTESET(SA0, SA1, SB0, SB1, SB2, SB3)                                        \
  acc[0][0] = __builtin_amdgcn_mfma_f32_16x16x32_bf16(SA0, SB0, acc[0][0], 0, 0, 0);    \
  acc[0][1] = __builtin_amdgcn_mfma_f32_16x16x32_bf16(SA0, SB1, acc[0][1], 0, 0, 0);    \
  acc[0][2] = __builtin_amdgcn_mfma_f32_16x16x32_bf16(SA0, SB2, acc[0][2], 0, 0, 0);    \
  acc[0][3] = __builtin_amdgcn_mfma_f32_16x16x32_bf16(SA0, SB3, acc[0][3], 0, 0, 0);    \
  acc[1][0] = __builtin_amdgcn_mfma_f32_16x16x32_bf16(SA1, SB0, acc[1][0], 0, 0, 0);    \
  acc[1][1] = __builtin_amdgcn_mfma_f32_16x16x32_bf16(SA1, SB1, acc[1][1], 0, 0, 0);    \
  acc[1][2] = __builtin_amdgcn_mfma_f32_16x16x32_bf16(SA1, SB2, acc[1][2], 0, 0, 0);    \
  acc[1][3] = __builtin_amdgcn_mfma_f32_16x16x32_bf16(SA1, SB3, acc[1][3], 0, 0, 0);

__global__ __launch_bounds__(256) void main_gemm(const unsigned short* __restrict__ A2,
                                                 const unsigned short* __restrict__ WB,
                                                 const float* __restrict__ bias,
                                                 float* __restrict__ out) {
  int tid = threadIdx.x;
  int lane = tid & 63, wv = tid >> 6;
  // XCD-affinity swizzle: xcd = bid&7; the 4 n-blocks of an m-tile have bids
  // differing by 8 (same XCD, adjacent dispatch) and xcd == sample9's producer
  // region (mt>>4) for residual-L2 reuse.
  int bid = blockIdx.x;
  int xcd = bid & 7;
  int wgrp = bid >> 3;            // 0..63
  int mt = xcd * 16 + (wgrp >> 2);  // 0..127
  int nb = wgrp & 3;              // 0..3
  int m0 = mt * 128;
  int n0 = nb * 64;
  int wm = wv * 32;
  int row = lane & 15, quad = lane >> 4;
  f32x4 acc[2][4] = {};

  int mb0 = (m0 + wm) >> 4;
  const unsigned short* ap0 = A2 + (size_t)mb0 * 72 * 512 + row * 32 + quad * 8;
  const unsigned short* ap1 = ap0 + (size_t)72 * 512;
  const unsigned short* bp = WB + (size_t)(nb * 4) * 512 + quad * 128 + row * 8;

  bf16x8 s0a0, s0a1, s0b0, s0b1, s0b2, s0b3;
  bf16x8 s1a0, s1a1, s1b0, s1b1, s1b2, s1b3;
  bf16x8 s2a0, s2a1, s2b0, s2b1, s2b2, s2b3;
  bf16x8 s3a0, s3a1, s3b0, s3b1, s3b2, s3b3;

  LOADSET(s0a0, s0a1, s0b0, s0b1, s0b2, s0b3, 0)
  LOADSET(s1a0, s1a1, s1b0, s1b1, s1b2, s1b3, 1)
  LOADSET(s2a0, s2a1, s2b0, s2b1, s2b2, s2b3, 2)
  LOADSET(s3a0, s3a1, s3b0, s3b1, s3b2, s3b3, 3)

#pragma unroll 1
  for (int t = 0; t < 68; t += 4) {
    COMPUTESET(s0a0, s0a1, s0b0, s0b1, s0b2, s0b3)
    LOADSET(s0a0, s0a1, s0b0, s0b1, s0b2, s0b3, t + 4)
    COMPUTESET(s1a0, s1a1, s1b0, s1b1, s1b2, s1b3)
    LOADSET(s1a0, s1a1, s1b0, s1b1, s1b2, s1b3, t + 5)
    COMPUTESET(s2a0, s2a1, s2b0, s2b1, s2b2, s2b3)
    LOADSET(s2a0, s2a1, s2b0, s2b1, s2b2, s2b3, t + 6)
    COMPUTESET(s3a0, s3a1, s3b0, s3b1, s3b2, s3b3)
    LOADSET(s3a0, s3a1, s3b0, s3b1, s3b2, s3b3, t + 7)
  }
  // epilogue tiles 68..71
  COMPUTESET(s0a0, s0a1, s0b0, s0b1, s0b2, s0b3)
  COMPUTESET(s1a0, s1a1, s1b0, s1b1, s1b2, s1b3)
  COMPUTESET(s2a0, s2a1, s2b0, s2b1, s2b2, s2b3)
  COMPUTESET(s3a0, s3a1, s3b0, s3b1, s3b2, s3b3)

  int b = m0 >> 12, hw0 = m0 & 4095;
#pragma unroll
  for (int j = 0; j < 4; ++j) {
    int o = n0 + j * 16 + row;
    float bo = bias[o];
#pragma unroll
    for (int i = 0; i < 2; ++i) {
      int hw = hw0 + wm + i * 16 + quad * 4;
      float4 v;
      v.x = acc[i][j][0] + bo;
      v.y = acc[i][j][1] + bo;
      v.z = acc[i][j][2] + bo;
      v.w = acc[i][j][3] + bo;
      *(float4*)(out + (((size_t)(b * COUT + o)) << 12) + hw) = v;
    }
  }
}

// ---------------- launch ----------------
extern "C" void kernel_launch(void* const* d_in, const int* in_sizes, int n_in,
                              void* d_out, int out_size, void* d_ws, size_t ws_size,
                              hipStream_t stream) {
  const float* x        = (const float*)d_in[0];
  const float* weight   = (const float*)d_in[1];
  const float* bias     = (const float*)d_in[2];
  const float* p_weight = (const float*)d_in[3];
  const float* p_bias   = (const float*)d_in[4];
  float* out = (float*)d_out;
  char* ws = (char*)d_ws;

  // workspace layout (bytes); total ~102 MB of 256 MiB
  const size_t OFF_XT   = 0;                          //  8,388,608  bf16 NHWC x
  const size_t OFF_WB   = OFF_XT + 8388608;           //  1,179,648  bf16 WB2
  const size_t OFF_PW   = OFF_WB + 1179648;           //    147,456  bf16
  const size_t OFF_P    = OFF_PW + 147456;            // 16,777,216  fp32 partials
  const size_t OFF_ZP   = OFF_P + 16777216;           //      8,192  zeropage
  const size_t OFF_A    = OFF_ZP + 8192;              // 75,497,472  bf16 A2

  unsigned short* xt    = (unsigned short*)(ws + OFF_XT);
  unsigned short* WB    = (unsigned short*)(ws + OFF_WB);
  unsigned short* PWs   = (unsigned short*)(ws + OFF_PW);
  float* Pbuf           = (float*)(ws + OFF_P);
  unsigned short* zerop = (unsigned short*)(ws + OFF_ZP);
  unsigned short* Amat  = (unsigned short*)(ws + OFF_A);

  prep_and_transpose<<<4096 + 2592, 256, 0, stream>>>(x, weight, p_weight, xt, WB, PWs, zerop);
  offset_conv_sk<<<dim3(MTOT / 64, SPLITK), 256, 0, stream>>>(xt, PWs, zerop, Pbuf);
  sample9<<<MTOT / 4, 256, 0, stream>>>(xt, Pbuf, p_bias, Amat);
  main_gemm<<<512, 256, 0, stream>>>(Amat, WB, bias, out);
}